// Round 7
// baseline (207.331 us; speedup 1.0000x reference)
//
#include <hip/hip_runtime.h>
#include <math.h>

// LDSLoss via histogram inversion + wide-MLP chunked streaming.
//   hot loop: per sample, sq = |in-tg|^2, bin = (i0,i1), ds_add_f32(hist[bin], sq)
//   epilogue: A = sum_b w_b*hist_b, B = sum_{isinf(w_b)} hist_b,
//             m = max_{hist_b>0, w finite} w_b;  out = scaling*(A + m*B)/(2N)
//
// R7 fix: R6 still had VGPR_Count=32 -> launch_bounds(1024,8) capped VGPR at 64
// and the allocator re-serialized the loads (MLP~1). Now:
//   - __launch_bounds__(512, 4): VGPR budget 128 -> 8 float4 loads can be live.
//   - chunk of 4 pairs: 8 INDEPENDENT global_load_dwordx4 issued back-to-back,
//     then process (counted vmcnt waits) -> MLP 8/wave, ~128 KB/CU in flight.
//   - edge pairs stored as float2 in LDS: find_bin = ONE ds_read_b64 (was 2xb32).
//   - GRID=1024 x BLOCK=512: 2 blocks/CU (81.6 KB LDS), 16 waves/CU.

#define BLOCK 512
#define GRID_BLKS 1024

// searchsorted(bins, x, 'right') - 1, clipped to [0, nb-1].
// Uniform guess (error <= 1; absmax=0 in R3/R4/R6) + branchless fixup using
// the exact float32 edge pair fetched with a single ds_read_b64.
__device__ __forceinline__ int find_bin(const float2* __restrict__ ep, int nb,
                                        float x, float lo, float inv_step) {
    int g = (int)floorf((x - lo) * inv_step);
    g = g < 0 ? 0 : (g > nb - 1 ? nb - 1 : g);
    float2 e = ep[g];                       // (edges[g], edges[g+1])
    g += (x >= e.y) ? 1 : 0;
    g -= (x < e.x) ? 1 : 0;
    return g < 0 ? 0 : (g > nb - 1 ? nb - 1 : g);
}

__device__ __forceinline__ void process_pair(
    float4 in, float4 tg,
    float* __restrict__ hist,
    const float2* __restrict__ ep0, const float2* __restrict__ ep1, int nb,
    float lo0, float inv0, float lo1, float inv1)
{
    float dA0 = in.x - tg.x, dA1 = in.y - tg.y;
    float sqA = dA0 * dA0 + dA1 * dA1;
    int iA0 = find_bin(ep0, nb, tg.x, lo0, inv0);
    int iA1 = find_bin(ep1, nb, tg.y, lo1, inv1);
    atomicAdd(&hist[iA0 * nb + iA1], sqA);      // ds_add_f32, fire-and-forget

    float dB0 = in.z - tg.z, dB1 = in.w - tg.w;
    float sqB = dB0 * dB0 + dB1 * dB1;
    int iB0 = find_bin(ep0, nb, tg.z, lo0, inv0);
    int iB1 = find_bin(ep1, nb, tg.w, lo1, inv1);
    atomicAdd(&hist[iB0 * nb + iB1], sqB);
}

__global__ void __launch_bounds__(BLOCK, 4)   // 4 waves/EU -> VGPR budget 128
lds_loss_hist(const float* __restrict__ input,
              const float* __restrict__ target,
              const float* __restrict__ smoothed,
              const float* __restrict__ bins0,
              const float* __restrict__ bins1,
              const float* __restrict__ scaling,
              int nb, long long n, long long nelem,
              double* __restrict__ accA,
              double* __restrict__ accB,
              unsigned int* __restrict__ accM,
              unsigned int* __restrict__ done_ctr,
              float* __restrict__ out)
{
    extern __shared__ __align__(16) float smem[];
    float2* ep0  = (float2*)smem;              // nb float2 (edges[j], edges[j+1])
    float2* ep1  = ep0 + nb;                   // nb float2
    float*  hist = (float*)(ep1 + nb);         // nb*nb floats

    const int nbnb = nb * nb;
    for (int i = threadIdx.x; i < nbnb; i += BLOCK) hist[i] = 0.0f;
    for (int i = threadIdx.x; i < nb; i += BLOCK) {
        ep0[i] = make_float2(bins0[i], bins0[i + 1]);
        ep1[i] = make_float2(bins1[i], bins1[i + 1]);
    }
    __syncthreads();

    const float lo0 = ep0[0].x, hi0 = ep0[nb - 1].y;
    const float lo1 = ep1[0].x, hi1 = ep1[nb - 1].y;
    const float inv0 = (float)nb / (hi0 - lo0);
    const float inv1 = (float)nb / (hi1 - lo1);

    const long long npair = n >> 1;
    const float4* in4 = (const float4*)input;
    const float4* tg4 = (const float4*)target;
    const long long S = (long long)gridDim.x * BLOCK;   // pair stride

    long long p = (long long)blockIdx.x * BLOCK + threadIdx.x;

    // chunks of 4 pairs: 8 independent 16B loads in flight, then process
    for (; p + 3 * S < npair; p += 4 * S) {
        float4 I0 = in4[p];
        float4 I1 = in4[p + S];
        float4 I2 = in4[p + 2 * S];
        float4 I3 = in4[p + 3 * S];
        float4 T0 = tg4[p];
        float4 T1 = tg4[p + S];
        float4 T2 = tg4[p + 2 * S];
        float4 T3 = tg4[p + 3 * S];
        __builtin_amdgcn_sched_barrier(0);   // all 8 loads issued before any use
        process_pair(I0, T0, hist, ep0, ep1, nb, lo0, inv0, lo1, inv1);
        process_pair(I1, T1, hist, ep0, ep1, nb, lo0, inv0, lo1, inv1);
        process_pair(I2, T2, hist, ep0, ep1, nb, lo0, inv0, lo1, inv1);
        process_pair(I3, T3, hist, ep0, ep1, nb, lo0, inv0, lo1, inv1);
    }
    // remainder pairs (up to 3)
    for (; p < npair; p += S) {
        process_pair(in4[p], tg4[p], hist, ep0, ep1, nb, lo0, inv0, lo1, inv1);
    }

    // odd-N single-sample tail (not hit for N=8M)
    if ((n & 1) && blockIdx.x == 0 && threadIdx.x == 0) {
        long long i = n - 1;
        float t0 = target[2 * i], t1 = target[2 * i + 1];
        float d0 = input[2 * i] - t0, d1 = input[2 * i + 1] - t1;
        float sq = d0 * d0 + d1 * d1;
        int j0 = find_bin(ep0, nb, t0, lo0, inv0);
        int j1 = find_bin(ep1, nb, t1, lo1, inv1);
        atomicAdd(&hist[j0 * nb + j1], sq);
    }
    __syncthreads();   // all ds_adds visible

    // Epilogue: fold histogram against the weight table (coalesced reads).
    // Classify by isinf(1/s) exactly like the reference.
    double A = 0.0, B = 0.0;
    float  m = 0.0f;
    for (int b = threadIdx.x; b < nbnb; b += BLOCK) {
        float h = hist[b];
        float s = smoothed[b];
        float w = 1.0f / s;
        if (isinf(w)) {
            B += (double)h;
        } else {
            A += (double)w * (double)h;
            if (h > 0.0f) m = fmaxf(m, w);
        }
    }

    #pragma unroll
    for (int off = 32; off > 0; off >>= 1) {
        A += __shfl_down(A, off, 64);
        B += __shfl_down(B, off, 64);
        m = fmaxf(m, __shfl_down(m, off, 64));
    }

    __shared__ double rA[BLOCK / 64], rB[BLOCK / 64];
    __shared__ float  rM[BLOCK / 64];
    int wave = threadIdx.x >> 6;
    int lane = threadIdx.x & 63;
    if (lane == 0) { rA[wave] = A; rB[wave] = B; rM[wave] = m; }
    __syncthreads();

    if (threadIdx.x == 0) {
        double ta = 0.0, tb = 0.0; float tm = 0.0f;
        #pragma unroll
        for (int w2 = 0; w2 < BLOCK / 64; ++w2) {
            ta += rA[w2]; tb += rB[w2]; tm = fmaxf(tm, rM[w2]);
        }
        atomicAdd(accA, ta);
        atomicAdd(accB, tb);
        atomicMax(accM, __float_as_uint(tm));   // positive floats: uint order == float
        __threadfence();
        unsigned int prev = atomicAdd(done_ctr, 1u);
        if (prev == gridDim.x - 1) {
            // last block: read back through atomic RMWs (coherent point)
            double Af = atomicAdd(accA, 0.0);
            double Bf = atomicAdd(accB, 0.0);
            float  Mf = __uint_as_float(atomicMax(accM, 0u));
            double v = (double)(*scaling) * (Af + (double)Mf * Bf) / (double)nelem;
            *out = (float)v;
        }
    }
}

extern "C" void kernel_launch(void* const* d_in, const int* in_sizes, int n_in,
                              void* d_out, int out_size, void* d_ws, size_t ws_size,
                              hipStream_t stream) {
    const float* input    = (const float*)d_in[0];
    const float* target   = (const float*)d_in[1];
    const float* smoothed = (const float*)d_in[2];
    const float* bins0    = (const float*)d_in[3];
    const float* bins1    = (const float*)d_in[4];
    const float* scaling  = (const float*)d_in[5];

    const long long nelem = in_sizes[0];       // N * 2
    const long long n     = nelem / 2;         // samples
    const int nb          = in_sizes[3] - 1;   // bins (edges - 1)

    double*       accA = (double*)d_ws;                    // @0
    double*       accB = accA + 1;                         // @8
    unsigned int* accM = (unsigned int*)(accB + 1);        // @16
    unsigned int* ctr  = accM + 1;                         // @20

    // d_ws is poisoned to 0xAA before every launch — zero the accumulators.
    hipMemsetAsync(d_ws, 0, 24, stream);

    long long blocks_needed = (n / 2 + BLOCK - 1) / BLOCK;
    int grid = (int)(blocks_needed < GRID_BLKS ? blocks_needed : GRID_BLKS);
    if (grid < 1) grid = 1;
    // shmem: 2*nb float2 edge-pairs + nb*nb hist. nb=99 -> 40,788 B -> 2 blk/CU.
    size_t shmem = ((size_t)nb * nb + 4 * (size_t)nb) * sizeof(float);

    lds_loss_hist<<<grid, BLOCK, shmem, stream>>>(
        input, target, smoothed, bins0, bins1, scaling,
        nb, n, nelem, accA, accB, accM, ctr, (float*)d_out);
}

// Round 9
// 197.437 us; speedup vs baseline: 1.0501x; 1.0501x over previous
//
#include <hip/hip_runtime.h>
#include <math.h>

// LDSLoss via histogram inversion + HAND-PIPELINED load stream (inline asm).
//   hot loop: per sample, sq = |in-tg|^2, bin=(i0,i1), ds_add_f32(hist[bin],sq)
//   epilogue: A = sum_b w_b*hist_b, B = sum_{isinf(w_b)} hist_b,
//             m = max_{hist_b>0,finite} w_b;  out = scaling*(A + m*B)/(2N)
//
// R8: R2-R7 all latency-bound; compiler repeatedly re-serialized streaming
// loads (VGPR_Count 24-32 despite generous budgets). Fix: inline-asm
// global_load_dwordx4 with hand-counted s_waitcnt vmcnt(N) — asm outputs are
// forced live, 16 loads in flight per wave. Rule #18: sched_barrier(0) after
// every waitcnt so consumers can't hoist above it. OOB slots load a clamped
// valid address (exec-uniform => vmcnt counting stays exact) and skip ds_add.

#define BLOCK 512
#define GRID_BLKS 768   // 3 blocks/CU * 256 CU at 40.8 KB LDS -> no residency tail
#define NSLOT 12        // 3 chunks x 4 pairs per macro-iteration

typedef __attribute__((ext_vector_type(4))) float f32x4;

#define GLOAD(dst, ptr) \
    asm volatile("global_load_dwordx4 %0, %1, off" : "=v"(dst) : "v"(ptr))
#define WAITVM(N)                                             \
    {                                                         \
        asm volatile("s_waitcnt vmcnt(" #N ")" ::: "memory"); \
        __builtin_amdgcn_sched_barrier(0);                    \
    }

// searchsorted(bins, x, 'right') - 1, clipped to [0, nb-1].
// Uniform guess (error <= 1; absmax=0 across R3/R4/R6/R7) + branchless fixup
// using the exact float32 edge pair (single ds_read_b64).
__device__ __forceinline__ int find_bin(const float2* __restrict__ ep, int nb,
                                        float x, float lo, float inv_step) {
    int g = (int)floorf((x - lo) * inv_step);
    g = g < 0 ? 0 : (g > nb - 1 ? nb - 1 : g);
    float2 e = ep[g];                       // (edges[g], edges[g+1])
    g += (x >= e.y) ? 1 : 0;
    g -= (x < e.x) ? 1 : 0;
    return g < 0 ? 0 : (g > nb - 1 ? nb - 1 : g);
}

__device__ __forceinline__ void process_pair(
    f32x4 in, f32x4 tg, bool valid,
    float* __restrict__ hist,
    const float2* __restrict__ ep0, const float2* __restrict__ ep1, int nb,
    float lo0, float inv0, float lo1, float inv1)
{
    float dA0 = in[0] - tg[0], dA1 = in[1] - tg[1];
    float sqA = dA0 * dA0 + dA1 * dA1;
    int iA0 = find_bin(ep0, nb, tg[0], lo0, inv0);
    int iA1 = find_bin(ep1, nb, tg[1], lo1, inv1);

    float dB0 = in[2] - tg[2], dB1 = in[3] - tg[3];
    float sqB = dB0 * dB0 + dB1 * dB1;
    int iB0 = find_bin(ep0, nb, tg[2], lo0, inv0);
    int iB1 = find_bin(ep1, nb, tg[3], lo1, inv1);

    if (valid) {
        atomicAdd(&hist[iA0 * nb + iA1], sqA);   // ds_add_f32
        atomicAdd(&hist[iB0 * nb + iB1], sqB);
    }
}

__global__ void __launch_bounds__(BLOCK)
lds_loss_hist(const float* __restrict__ input,
              const float* __restrict__ target,
              const float* __restrict__ smoothed,
              const float* __restrict__ bins0,
              const float* __restrict__ bins1,
              const float* __restrict__ scaling,
              int nb, long long n, long long nelem,
              double* __restrict__ accA,
              double* __restrict__ accB,
              unsigned int* __restrict__ accM,
              unsigned int* __restrict__ done_ctr,
              float* __restrict__ out)
{
    extern __shared__ __align__(16) float smem[];
    float2* ep0  = (float2*)smem;              // nb float2 (edges[j], edges[j+1])
    float2* ep1  = ep0 + nb;                   // nb float2
    float*  hist = (float*)(ep1 + nb);         // nb*nb floats

    const int nbnb = nb * nb;
    for (int i = threadIdx.x; i < nbnb; i += BLOCK) hist[i] = 0.0f;
    for (int i = threadIdx.x; i < nb; i += BLOCK) {
        ep0[i] = make_float2(bins0[i], bins0[i + 1]);
        ep1[i] = make_float2(bins1[i], bins1[i + 1]);
    }
    __syncthreads();

    const float lo0 = ep0[0].x, hi0 = ep0[nb - 1].y;
    const float lo1 = ep1[0].x, hi1 = ep1[nb - 1].y;
    const float inv0 = (float)nb / (hi0 - lo0);
    const float inv1 = (float)nb / (hi1 - lo1);

    const long long npair = n >> 1;
    const f32x4* in4 = (const f32x4*)input;
    const f32x4* tg4 = (const f32x4*)target;
    const long long S = (long long)gridDim.x * BLOCK;   // pair stride

    // wave-uniform trip count (scalar operands only)
    const long long MACRO = (long long)NSLOT * S;
    const long long niter = (npair + MACRO - 1) / MACRO;

    long long base = (long long)blockIdx.x * BLOCK + threadIdx.x;

    for (long long it = 0; it < niter; ++it, base += MACRO) {
        // slot addresses (clamped) + validity — fully unrolled, all static idx
        const f32x4* aI[NSLOT];
        const f32x4* aT[NSLOT];
        bool         vv[NSLOT];
        #pragma unroll
        for (int j = 0; j < NSLOT; ++j) {
            long long q = base + (long long)j * S;
            vv[j] = q < npair;
            q = vv[j] ? q : (npair - 1);
            aI[j] = in4 + q;
            aT[j] = tg4 + q;
        }

        f32x4 A0, A1, A2, A3, Ax0, Ax1, Ax2, Ax3;   // chunk 0
        f32x4 B0, B1, B2, B3, Bx0, Bx1, Bx2, Bx3;   // chunk 1
        f32x4 C0, C1, C2, C3, Cx0, Cx1, Cx2, Cx3;   // chunk 2

        // issue chunk 0 + chunk 1 : 16 loads in flight
        GLOAD(A0, aI[0]);  GLOAD(A1, aI[1]);  GLOAD(A2, aI[2]);  GLOAD(A3, aI[3]);
        GLOAD(Ax0, aT[0]); GLOAD(Ax1, aT[1]); GLOAD(Ax2, aT[2]); GLOAD(Ax3, aT[3]);
        GLOAD(B0, aI[4]);  GLOAD(B1, aI[5]);  GLOAD(B2, aI[6]);  GLOAD(B3, aI[7]);
        GLOAD(Bx0, aT[4]); GLOAD(Bx1, aT[5]); GLOAD(Bx2, aT[6]); GLOAD(Bx3, aT[7]);

        WAITVM(8);   // chunk 0 ready, chunk 1 still in flight
        process_pair(A0, Ax0, vv[0], hist, ep0, ep1, nb, lo0, inv0, lo1, inv1);
        process_pair(A1, Ax1, vv[1], hist, ep0, ep1, nb, lo0, inv0, lo1, inv1);
        process_pair(A2, Ax2, vv[2], hist, ep0, ep1, nb, lo0, inv0, lo1, inv1);
        process_pair(A3, Ax3, vv[3], hist, ep0, ep1, nb, lo0, inv0, lo1, inv1);

        // issue chunk 2 while chunk 1 completes
        GLOAD(C0, aI[8]);  GLOAD(C1, aI[9]);  GLOAD(C2, aI[10]); GLOAD(C3, aI[11]);
        GLOAD(Cx0, aT[8]); GLOAD(Cx1, aT[9]); GLOAD(Cx2, aT[10]); GLOAD(Cx3, aT[11]);

        WAITVM(8);   // chunk 1 ready, chunk 2 in flight
        process_pair(B0, Bx0, vv[4], hist, ep0, ep1, nb, lo0, inv0, lo1, inv1);
        process_pair(B1, Bx1, vv[5], hist, ep0, ep1, nb, lo0, inv0, lo1, inv1);
        process_pair(B2, Bx2, vv[6], hist, ep0, ep1, nb, lo0, inv0, lo1, inv1);
        process_pair(B3, Bx3, vv[7], hist, ep0, ep1, nb, lo0, inv0, lo1, inv1);

        WAITVM(0);   // chunk 2 ready
        process_pair(C0, Cx0, vv[8],  hist, ep0, ep1, nb, lo0, inv0, lo1, inv1);
        process_pair(C1, Cx1, vv[9],  hist, ep0, ep1, nb, lo0, inv0, lo1, inv1);
        process_pair(C2, Cx2, vv[10], hist, ep0, ep1, nb, lo0, inv0, lo1, inv1);
        process_pair(C3, Cx3, vv[11], hist, ep0, ep1, nb, lo0, inv0, lo1, inv1);
    }

    // odd-N single-sample tail (not hit for N=8M)
    if ((n & 1) && blockIdx.x == 0 && threadIdx.x == 0) {
        long long i = n - 1;
        float t0 = target[2 * i], t1 = target[2 * i + 1];
        float d0 = input[2 * i] - t0, d1 = input[2 * i + 1] - t1;
        float sq = d0 * d0 + d1 * d1;
        int j0 = find_bin(ep0, nb, t0, lo0, inv0);
        int j1 = find_bin(ep1, nb, t1, lo1, inv1);
        atomicAdd(&hist[j0 * nb + j1], sq);
    }
    __syncthreads();   // all ds_adds visible

    // Epilogue: fold histogram against the weight table (coalesced reads).
    double A = 0.0, B = 0.0;
    float  m = 0.0f;
    for (int b = threadIdx.x; b < nbnb; b += BLOCK) {
        float h = hist[b];
        float s = smoothed[b];
        float w = 1.0f / s;
        if (isinf(w)) {
            B += (double)h;
        } else {
            A += (double)w * (double)h;
            if (h > 0.0f) m = fmaxf(m, w);
        }
    }

    #pragma unroll
    for (int off = 32; off > 0; off >>= 1) {
        A += __shfl_down(A, off, 64);
        B += __shfl_down(B, off, 64);
        m = fmaxf(m, __shfl_down(m, off, 64));
    }

    __shared__ double rA[BLOCK / 64], rB[BLOCK / 64];
    __shared__ float  rM[BLOCK / 64];
    int wave = threadIdx.x >> 6;
    int lane = threadIdx.x & 63;
    if (lane == 0) { rA[wave] = A; rB[wave] = B; rM[wave] = m; }
    __syncthreads();

    if (threadIdx.x == 0) {
        double ta = 0.0, tb = 0.0; float tm = 0.0f;
        #pragma unroll
        for (int w2 = 0; w2 < BLOCK / 64; ++w2) {
            ta += rA[w2]; tb += rB[w2]; tm = fmaxf(tm, rM[w2]);
        }
        atomicAdd(accA, ta);
        atomicAdd(accB, tb);
        atomicMax(accM, __float_as_uint(tm));   // positive floats: uint order == float
        __threadfence();
        unsigned int prev = atomicAdd(done_ctr, 1u);
        if (prev == gridDim.x - 1) {
            double Af = atomicAdd(accA, 0.0);
            double Bf = atomicAdd(accB, 0.0);
            float  Mf = __uint_as_float(atomicMax(accM, 0u));
            double v = (double)(*scaling) * (Af + (double)Mf * Bf) / (double)nelem;
            *out = (float)v;
        }
    }
}

extern "C" void kernel_launch(void* const* d_in, const int* in_sizes, int n_in,
                              void* d_out, int out_size, void* d_ws, size_t ws_size,
                              hipStream_t stream) {
    const float* input    = (const float*)d_in[0];
    const float* target   = (const float*)d_in[1];
    const float* smoothed = (const float*)d_in[2];
    const float* bins0    = (const float*)d_in[3];
    const float* bins1    = (const float*)d_in[4];
    const float* scaling  = (const float*)d_in[5];

    const long long nelem = in_sizes[0];       // N * 2
    const long long n     = nelem / 2;         // samples
    const int nb          = in_sizes[3] - 1;   // bins (edges - 1)

    double*       accA = (double*)d_ws;                    // @0
    double*       accB = accA + 1;                         // @8
    unsigned int* accM = (unsigned int*)(accB + 1);        // @16
    unsigned int* ctr  = accM + 1;                         // @20

    // d_ws is poisoned to 0xAA before every launch — zero the accumulators.
    hipMemsetAsync(d_ws, 0, 24, stream);

    long long blocks_needed = (n / 2 + BLOCK - 1) / BLOCK;
    int grid = (int)(blocks_needed < GRID_BLKS ? blocks_needed : GRID_BLKS);
    if (grid < 1) grid = 1;
    // shmem: 2*nb float2 edge-pairs + nb*nb hist. nb=99 -> 40,788 B -> 3 blk/CU.
    size_t shmem = ((size_t)nb * nb + 4 * (size_t)nb) * sizeof(float);

    lds_loss_hist<<<grid, BLOCK, shmem, stream>>>(
        input, target, smoothed, bins0, bins1, scaling,
        nb, n, nelem, accA, accB, accM, ctr, (float*)d_out);
}